// Round 10
// baseline (67.464 us; speedup 1.0000x reference)
//
#include <hip/hip_runtime.h>

#define NHEADS 8
#define NN     128
#define NCELL  (NN * NN)       // 16384 floats = 64 KiB
#define NT     1024            // 16 waves, 4/SIMD
#define SCALE_F 10.0f

typedef float nfloat4 __attribute__((ext_vector_type(4)));

// Blocked Floyd-Warshall, B=16, one block (1024 thr) per graph, 1 block/CU.
// Thread t: rgrp=t>>5 (rows 4rgrp..+3), cgrp=t&31 (cols 4cgrp..+3).
// dd[4][4] register-resident (square tile balances C's LDS read amortization).
// Per step kb (2 barriers):
//   waves 0-3: redundant in-place shfl-closure of diag tile (exact under the
//     benign race: inputs in [D*,D] -> closure()=D*), own-wave lgkmcnt, then
//     B' (R_new = D* (x) R_old), 1 row x 8 cols per lane            ; bar
//   C: dd = min(dd, C_old[i][m] + R_new[m][j]); extract(kb+1)       ; bar
//
// LDS float offsets:
#define RP_O 0        // [16][128] R_old
#define RP_N 2048     // [16][128] R_new
#define CP_As 4096    // [16][132] C_oldT parity 0
#define CP_Bs 6208    // [16][132] parity 1
#define DPS  8320     // [16][20]  diag tile, closed in place to D*
#define RED  8640

__device__ __forceinline__ void extract_panels(const float (&dd)[4][4], float* lds,
                                               const int kbn, const int rgrp,
                                               const int cgrp, const int cpbase)
{
    if ((rgrp >> 2) == kbn) {                 // row-panel owners (2 waves)
        const int qb = (rgrp & 3) << 2;
        #pragma unroll
        for (int rr = 0; rr < 4; ++rr) {
            *reinterpret_cast<float4*>(&lds[RP_O + (qb+rr)*128 + (cgrp<<2)]) =
                make_float4(dd[rr][0], dd[rr][1], dd[rr][2], dd[rr][3]);
        }
        if ((cgrp >> 2) == kbn) {             // diag owners (16 threads)
            const int p = (cgrp & 3) << 2;
            #pragma unroll
            for (int rr = 0; rr < 4; ++rr) {
                *reinterpret_cast<float4*>(&lds[DPS + (qb+rr)*20 + p]) =
                    make_float4(dd[rr][0], dd[rr][1], dd[rr][2], dd[rr][3]);
            }
        }
    }
    if ((cgrp >> 2) == kbn) {                 // col-panel owners (128 threads)
        const int mb = (cgrp & 3) << 2;
        #pragma unroll
        for (int e = 0; e < 4; ++e) {
            *reinterpret_cast<float4*>(&lds[cpbase + (mb+e)*132 + (rgrp<<2)]) =
                make_float4(dd[0][e], dd[1][e], dd[2][e], dd[3][e]);
        }
    }
}

// waves 0-3: redundant in-place closure of DPS (16x16) + B' into RP_N.
__device__ __forceinline__ void closure_bprime(float* lds, const int t)
{
    if (t < 256) {
        const float INF = __builtin_huge_valf();
        const int l  = t & 63;
        const int i  = l & 15;        // tile row owned in closure
        const int jq = l >> 4;        // col quad owned in closure
        const int w  = t >> 6;
        float4 v = *reinterpret_cast<const float4*>(&lds[DPS + i*20 + (jq<<2)]);
        float T0 = v.x, T1 = v.y, T2 = v.z, T3 = v.w;
        #pragma unroll
        for (int k = 0; k < 16; ++k) {
            const int ksrc = ((k >> 2) << 4) | i;
            float dik;
            switch (k & 3) {
                case 0: dik = __shfl(T0, ksrc); break;
                case 1: dik = __shfl(T1, ksrc); break;
                case 2: dik = __shfl(T2, ksrc); break;
                default: dik = __shfl(T3, ksrc); break;
            }
            const int rsrc = (jq << 4) | k;
            const float r0 = __shfl(T0, rsrc);
            const float r1 = __shfl(T1, rsrc);
            const float r2 = __shfl(T2, rsrc);
            const float r3 = __shfl(T3, rsrc);
            T0 = fminf(T0, dik + r0);
            T1 = fminf(T1, dik + r1);
            T2 = fminf(T2, dik + r2);
            T3 = fminf(T3, dik + r3);
        }
        *reinterpret_cast<float4*>(&lds[DPS + i*20 + (jq<<2)]) =
            make_float4(T0, T1, T2, T3);
        asm volatile("s_waitcnt lgkmcnt(0)" ::: "memory");
        // B': output row r, cols j0..j0+7
        const int r  = (w << 2) | jq;
        const int j0 = i << 3;
        float da[16];
        #pragma unroll
        for (int q = 0; q < 4; ++q) {
            float4 d4 = *reinterpret_cast<const float4*>(&lds[DPS + r*20 + (q<<2)]);
            da[4*q+0]=d4.x; da[4*q+1]=d4.y; da[4*q+2]=d4.z; da[4*q+3]=d4.w;
        }
        float aA[8];
        #pragma unroll
        for (int e = 0; e < 8; ++e) aA[e] = INF;
        #pragma unroll
        for (int mp = 0; mp < 8; ++mp) {
            const int m0 = 2*mp, m1 = 2*mp + 1;
            float4 ra0 = *reinterpret_cast<const float4*>(&lds[RP_O + m0*128 + j0]);
            float4 ra1 = *reinterpret_cast<const float4*>(&lds[RP_O + m0*128 + j0 + 4]);
            float4 rb0 = *reinterpret_cast<const float4*>(&lds[RP_O + m1*128 + j0]);
            float4 rb1 = *reinterpret_cast<const float4*>(&lds[RP_O + m1*128 + j0 + 4]);
            const float a0[4] = {ra0.x, ra0.y, ra0.z, ra0.w};
            const float a1[4] = {ra1.x, ra1.y, ra1.z, ra1.w};
            const float b0[4] = {rb0.x, rb0.y, rb0.z, rb0.w};
            const float b1[4] = {rb1.x, rb1.y, rb1.z, rb1.w};
            #pragma unroll
            for (int e = 0; e < 4; ++e) {
                aA[e]   = fminf(fminf(aA[e],   da[m0] + a0[e]), da[m1] + b0[e]);
                aA[4+e] = fminf(fminf(aA[4+e], da[m0] + a1[e]), da[m1] + b1[e]);
            }
        }
        *reinterpret_cast<float4*>(&lds[RP_N + r*128 + j0]) =
            make_float4(aA[0], aA[1], aA[2], aA[3]);
        *reinterpret_cast<float4*>(&lds[RP_N + r*128 + j0 + 4]) =
            make_float4(aA[4], aA[5], aA[6], aA[7]);
    }
}

// C: dd = min(dd, C_old[i][m] + R_new[m][j]) over 16 m
__device__ __forceinline__ void cphase(float (&dd)[4][4], float* lds,
                                       const int rgrp, const int cgrp,
                                       const int cpbase)
{
    #pragma unroll
    for (int mq = 0; mq < 4; ++mq) {
        float4 cp[4], ra[4];
        #pragma unroll
        for (int e = 0; e < 4; ++e) {
            const int m = 4*mq + e;
            cp[e] = *reinterpret_cast<const float4*>(&lds[cpbase + m*132 + (rgrp<<2)]);
            ra[e] = *reinterpret_cast<const float4*>(&lds[RP_N + m*128 + (cgrp<<2)]);
        }
        #pragma unroll
        for (int ee = 0; ee < 2; ++ee) {
            const float c0[4] = {cp[2*ee].x, cp[2*ee].y, cp[2*ee].z, cp[2*ee].w};
            const float c1[4] = {cp[2*ee+1].x, cp[2*ee+1].y, cp[2*ee+1].z, cp[2*ee+1].w};
            const float r0[4] = {ra[2*ee].x, ra[2*ee].y, ra[2*ee].z, ra[2*ee].w};
            const float r1[4] = {ra[2*ee+1].x, ra[2*ee+1].y, ra[2*ee+1].z, ra[2*ee+1].w};
            #pragma unroll
            for (int rr = 0; rr < 4; ++rr) {
                #pragma unroll
                for (int e = 0; e < 4; ++e) {
                    dd[rr][e] = fminf(fminf(dd[rr][e], c0[rr] + r0[e]), c1[rr] + r1[e]);
                }
            }
        }
    }
}

__global__ __launch_bounds__(NT, 4)
void spb_fw_kernel(const int* __restrict__ edge_index,
                   const float* __restrict__ edge_weight,
                   const int num_edges, const int epg,
                   float* __restrict__ out)
{
    __shared__ float lds[NCELL];
    const float INF = __builtin_huge_valf();
    const int t    = threadIdx.x;
    const int g    = blockIdx.x;
    const int cgrp = t & 31;
    const int rgrp = t >> 5;

    // ---- prefetch this block's edges (2/thread) ----
    const int ebase = g * epg;
    int es[2], ed[2]; float ewt[2];
    #pragma unroll
    for (int k = 0; k < 2; ++k) {
        int e = t + (k << 10);
        e = (e < epg) ? e : (epg - 1);      // clamp; dup scatter idempotent
        es[k]  = edge_index[ebase + e];
        ed[k]  = edge_index[num_edges + ebase + e];
        ewt[k] = edge_weight[ebase + e];
    }

    // ---- init matrix (swizzled: elem(i,col) at i*128 + (col ^ ((i&7)<<2))) ----
    #pragma unroll
    for (int c = 0; c < 4; ++c) {
        const int m   = t + (c << 10);
        const int i   = m >> 5;
        const int scm = m & 31;
        const int c0  = (scm ^ (i & 7)) << 2;
        float4 v;
        v.x = (c0 + 0 == i) ? 0.0f : INF;
        v.y = (c0 + 1 == i) ? 0.0f : INF;
        v.z = (c0 + 2 == i) ? 0.0f : INF;
        v.w = (c0 + 3 == i) ? 0.0f : INF;
        *reinterpret_cast<float4*>(&lds[m << 2]) = v;
    }
    __syncthreads();

    // ---- scatter edges (atomicMin on int view of positive floats) ----
    #pragma unroll
    for (int k = 0; k < 2; ++k) {
        const int u = es[k] - g * NN;
        const int v = ed[k] - g * NN;
        if (u != v && (unsigned)u < (unsigned)NN && (unsigned)v < (unsigned)NN) {
            const int a = (u << 7) + (v ^ ((u & 7) << 2));
            atomicMin(reinterpret_cast<int*>(&lds[a]), __float_as_int(ewt[k]));
        }
    }
    __syncthreads();

    // ---- load dd[4][4]: dd[rr][e] = d[4rgrp+rr][4cgrp+e] ----
    float dd[4][4];
    #pragma unroll
    for (int rr = 0; rr < 4; ++rr) {
        const int i = (rgrp << 2) + rr;
        float4 v = *reinterpret_cast<const float4*>(
            &lds[(i << 7) + ((cgrp ^ (i & 7)) << 2)]);
        dd[rr][0]=v.x; dd[rr][1]=v.y; dd[rr][2]=v.z; dd[rr][3]=v.w;
    }
    __syncthreads();   // matrix region dead; panels may be written

    // ---- blocked FW: 8 steps, 2 barriers each (ROLLED loop) ----
    extract_panels(dd, lds, 0, rgrp, cgrp, CP_As);
    __syncthreads();
    #pragma unroll 1
    for (int kb = 0; kb < 8; ++kb) {
        closure_bprime(lds, t);
        __syncthreads();
        cphase(dd, lds, rgrp, cgrp, (kb & 1) ? CP_Bs : CP_As);
        if (kb < 7)
            extract_panels(dd, lds, kb + 1, rgrp, cgrp, ((kb+1) & 1) ? CP_Bs : CP_As);
        __syncthreads();
    }

    // ---- reductions (max finite, global max) ----
    float mF = 0.0f, mA = 0.0f;
    #pragma unroll
    for (int rr = 0; rr < 4; ++rr)
        #pragma unroll
        for (int j = 0; j < 4; ++j) {
            const float v = dd[rr][j];
            mA = fmaxf(mA, v);
            mF = fmaxf(mF, v < INF ? v : 0.0f);
        }
    #pragma unroll
    for (int o = 32; o > 0; o >>= 1) {
        mF = fmaxf(mF, __shfl_xor(mF, o));
        mA = fmaxf(mA, __shfl_xor(mA, o));
    }
    if ((t & 63) == 0) {
        lds[RED + ((t >> 6) << 1)]     = mF;
        lds[RED + ((t >> 6) << 1) + 1] = mA;
    }
    __syncthreads();
    mF = lds[RED]; mA = lds[RED + 1];
    #pragma unroll
    for (int wv = 1; wv < 16; ++wv) {
        mF = fmaxf(mF, lds[RED + wv*2]);
        mA = fmaxf(mA, lds[RED + wv*2 + 1]);
    }
    const float twoF  = 2.0f * mF;
    const float maxv  = fmaxf((mA == INF) ? twoF : mF, 1e-8f);
    const float nscal = -SCALE_F / maxv;

    // ---- normalize in registers, store 8 heads (coalesced, nontemporal) ----
    float* const outg = out + (size_t)g * (NHEADS * NCELL);
    #pragma unroll
    for (int rr = 0; rr < 4; ++rr) {
        const int i = (rgrp << 2) + rr;
        nfloat4 v;
        v.x = ((dd[rr][0] == INF) ? twoF : dd[rr][0]) * nscal;
        v.y = ((dd[rr][1] == INF) ? twoF : dd[rr][1]) * nscal;
        v.z = ((dd[rr][2] == INF) ? twoF : dd[rr][2]) * nscal;
        v.w = ((dd[rr][3] == INF) ? twoF : dd[rr][3]) * nscal;
        const int o = (i << 7) + (cgrp << 2);
        #pragma unroll
        for (int h = 0; h < NHEADS; ++h) {
            __builtin_nontemporal_store(
                v, reinterpret_cast<nfloat4*>(&outg[h * NCELL + o]));
        }
    }
}

extern "C" void kernel_launch(void* const* d_in, const int* in_sizes, int n_in,
                              void* d_out, int out_size, void* d_ws, size_t ws_size,
                              hipStream_t stream)
{
    const int*   edge_index  = (const int*)d_in[0];
    const float* edge_w      = (const float*)d_in[1];
    const int E    = in_sizes[1];
    const int Ntot = in_sizes[2];
    const int G    = Ntot / NN;
    const int epg  = E / G;
    float* out = (float*)d_out;
    spb_fw_kernel<<<G, NT, 0, stream>>>(edge_index, edge_w, E, epg, out);
}